// Round 21
// baseline (478.008 us; speedup 1.0000x reference)
//
#include <hip/hip_runtime.h>
#include <hip/hip_bf16.h>

#define DEVI __device__ __forceinline__
#define AS1 __attribute__((address_space(1)))
#define AS3 __attribute__((address_space(3)))

typedef short bf16x8 __attribute__((ext_vector_type(8)));
typedef float f32x4  __attribute__((ext_vector_type(4)));
typedef unsigned short u16x4 __attribute__((ext_vector_type(4)));

// Problem constants (B=32, H=W=56, C=256, wh=ww=7, shift=3, heads=8, hd=32)
constexpr int MROWS = 100352;            // 32 * 64 * 49 window-order rows

// window-order row -> flat token index (b*3136 + h*56 + w).
DEVI int win_row_to_token(int r) {
  int b   = r / 3136;
  int rem = r - b * 3136;
  int wi  = rem / 49;
  int t   = rem - wi * 49;
  int nwh = wi >> 3, nww = wi & 7;
  int th = t / 7, tw = t - th * 7;
  int h = nwh * 7 + th + 3; if (h >= 56) h -= 56;
  int w = nww * 7 + tw + 3; if (w >= 56) w -= 56;
  return b * 3136 + h * 56 + w;
}

DEVI unsigned short f2bf(float f) {
  __hip_bfloat16 h = __float2bfloat16(f);
  return __builtin_bit_cast(unsigned short, h);
}

DEVI float gelu_t(float v) {
  // tanh-form GELU: v * sigmoid(2*0.7978845608*(v + 0.044715 v^3))
  float u2 = v * (1.5957691216f + 0.1426930877f * v * v);
  float e  = __expf(u2);
  return v * e / (e + 1.0f);
}

// -------- pack W (fp32 [N][K]) -> MFMA-frag-ordered bf16 --------
__global__ void pack_kernel(const float* __restrict__ W, __hip_bfloat16* __restrict__ Wp,
                            int N, int K) {
  long t = (long)blockIdx.x * 256 + threadIdx.x;   // one bf16x8 per thread
  long total = (long)N * K / 8;
  if (t >= total) return;
  int l  = (int)(t & 63);
  long f = t >> 6;
  int ni = (int)(f & 3);
  int kk = (int)((f >> 2) & 7);
  long r = f >> 5;                 // nb*KB + kb
  int KB = K / 256;
  int kb = (int)(r % KB);
  int nb = (int)(r / KB);
  int row  = nb * 64 + (l & 15) + ni * 16;
  int col0 = kb * 256 + kk * 32 + (l >> 4) * 8;
  const float* src = W + (size_t)row * K + col0;
  u16x4 lo, hi;
  #pragma unroll
  for (int e = 0; e < 4; ++e) { lo[e] = f2bf(src[e]); hi[e] = f2bf(src[4 + e]); }
  *(u16x4*)(Wp + t * 8)     = lo;
  *(u16x4*)(Wp + t * 8 + 4) = hi;
}

// ---------------- LayerNorm 1 (one wave per token row, windowed gather) ----------------
__global__ __launch_bounds__(256) void ln_kernel(
    const float* __restrict__ xin, const float* __restrict__ g,
    const float* __restrict__ b, __hip_bfloat16* __restrict__ outb)
{
  int r = blockIdx.x * 4 + (threadIdx.x >> 6);
  int l = threadIdx.x & 63;
  int tok = win_row_to_token(r);
  float4 xv = *(const float4*)&xin[(size_t)tok * 256 + l * 4];
  float s = xv.x + xv.y + xv.z + xv.w;
  float q = xv.x * xv.x + xv.y * xv.y + xv.z * xv.z + xv.w * xv.w;
  #pragma unroll
  for (int off = 32; off; off >>= 1) { s += __shfl_xor(s, off); q += __shfl_xor(q, off); }
  float mu = s * (1.0f / 256.0f);
  float var = q * (1.0f / 256.0f) - mu * mu;
  float rs = rsqrtf(var + 1e-5f);
  float4 gv = *(const float4*)&g[l * 4];
  float4 bv = *(const float4*)&b[l * 4];
  ushort4 st;
  st.x = f2bf((xv.x - mu) * rs * gv.x + bv.x);
  st.y = f2bf((xv.y - mu) * rs * gv.y + bv.y);
  st.z = f2bf((xv.z - mu) * rs * gv.z + bv.z);
  st.w = f2bf((xv.w - mu) * rs * gv.w + bv.w);
  *(ushort4*)&outb[(size_t)r * 256 + l * 4] = st;
}

// ------------- A-resident GEMM for QKV (R13-validated) -------------
__global__ __launch_bounds__(256, 3) void gemm_qkv(
    const __hip_bfloat16* __restrict__ A,
    const __hip_bfloat16* __restrict__ Wp,   // frag-packed, N=768 K=256
    const float* __restrict__ bias,
    __hip_bfloat16* __restrict__ outb)
{
  constexpr int CB = 3;
  __shared__ __align__(16) __hip_bfloat16 Al[64 * 256];   // 32KB

  const int tid = threadIdx.x;
  const int w = tid >> 6, l = tid & 63;
  const int g = l >> 4, lm = l & 15;

  const int nwg = gridDim.x;
  int bswz = (blockIdx.x & 7) * (nwg >> 3) + (blockIdx.x >> 3);
  const int mt = bswz / CB;
  const int cb = bswz - mt * CB;

  const char* At = (const char*)A + (size_t)mt * 64 * 512;
  char* AlB = (char*)Al;
  const int r0  = tid >> 5;
  const int usw = ((tid & 31) ^ r0) << 4;
  const int lmx = lm & 7;
  const int arow = lm * 512;

  const __hip_bfloat16* WpB = Wp + (size_t)(cb * 4 + w) * 16384;
  const int colb = cb * 256 + w * 64 + g * 4;

  f32x4 acc[4][4];
  {
    f32x4 bias_v[4];
    #pragma unroll
    for (int ni = 0; ni < 4; ++ni) bias_v[ni] = *(const f32x4*)&bias[colb + ni * 16];
    #pragma unroll
    for (int mi = 0; mi < 4; ++mi)
      #pragma unroll
      for (int ni = 0; ni < 4; ++ni) acc[mi][ni] = bias_v[ni];
  }

  #pragma unroll
  for (int j = 0; j < 8; ++j)
    __builtin_amdgcn_global_load_lds(
        (const AS1 void*)(At + (long)(j * 8 + r0) * 512 + usw),
        (AS3 void*)(AlB + j * 4096 + w * 1024), 16, 0, 0);
  asm volatile("s_waitcnt vmcnt(0)" ::: "memory");
  __syncthreads();

  #pragma unroll
  for (int kk = 0; kk < 8; ++kk) {
    bf16x8 bf[4], af[4];
    #pragma unroll
    for (int ni = 0; ni < 4; ++ni)
      bf[ni] = *(const bf16x8*)(WpB + ((kk * 4 + ni) * 64 + l) * 8);
    #pragma unroll
    for (int mi = 0; mi < 4; ++mi)
      af[mi] = *(const bf16x8*)(AlB + arow + mi * 8192 + ((((kk << 2) | g) ^ lmx) << 4));
    #pragma unroll
    for (int mi = 0; mi < 4; ++mi)
      #pragma unroll
      for (int ni = 0; ni < 4; ++ni)
        acc[mi][ni] = __builtin_amdgcn_mfma_f32_16x16x32_bf16(bf[ni], af[mi], acc[mi][ni], 0, 0, 0);
  }

  #pragma unroll
  for (int mi = 0; mi < 4; ++mi) {
    int grow = mt * 64 + mi * 16 + lm;
    __hip_bfloat16* rp = outb + (size_t)grow * 768 + colb;
    #pragma unroll
    for (int ni = 0; ni < 4; ++ni) {
      u16x4 st = { f2bf(acc[mi][ni][0]), f2bf(acc[mi][ni][1]),
                   f2bf(acc[mi][ni][2]), f2bf(acc[mi][ni][3]) };
      *(u16x4*)(rp + ni * 16) = st;
    }
  }
}

// ------------- PROJ + residual + LN2 fused (R14-validated) -------------
__global__ __launch_bounds__(256, 3) void proj_ln2(
    const __hip_bfloat16* __restrict__ A,    // attn_o (window order)
    const __hip_bfloat16* __restrict__ Wp,   // frag-packed proj, N=256 K=256
    const float* __restrict__ bias,
    const float* __restrict__ xres,          // x (token order)
    const float* __restrict__ g2, const float* __restrict__ b2,
    float* __restrict__ outf,
    __hip_bfloat16* __restrict__ alnout)
{
  __shared__ __align__(16) __hip_bfloat16 Al[64 * 256];   // 32KB
  __shared__ float2 Sst[4][16][4];                        // 2KB (mi, lm, w)

  const int tid = threadIdx.x;
  const int w = tid >> 6, l = tid & 63;
  const int g = l >> 4, lm = l & 15;

  const int nwg = gridDim.x;
  int bswz = (blockIdx.x & 7) * (nwg >> 3) + (blockIdx.x >> 3);
  const int mt = bswz;

  const char* At = (const char*)A + (size_t)mt * 64 * 512;
  char* AlB = (char*)Al;
  const int r0  = tid >> 5;
  const int usw = ((tid & 31) ^ r0) << 4;
  const int lmx = lm & 7;
  const int arow = lm * 512;

  const __hip_bfloat16* WpB = Wp + (size_t)w * 16384;
  const int colb = w * 64 + g * 4;

  f32x4 acc[4][4];
  {
    f32x4 bias_v[4];
    #pragma unroll
    for (int ni = 0; ni < 4; ++ni) bias_v[ni] = *(const f32x4*)&bias[colb + ni * 16];
    #pragma unroll
    for (int mi = 0; mi < 4; ++mi)
      #pragma unroll
      for (int ni = 0; ni < 4; ++ni) acc[mi][ni] = bias_v[ni];
  }

  #pragma unroll
  for (int j = 0; j < 8; ++j)
    __builtin_amdgcn_global_load_lds(
        (const AS1 void*)(At + (long)(j * 8 + r0) * 512 + usw),
        (AS3 void*)(AlB + j * 4096 + w * 1024), 16, 0, 0);
  asm volatile("s_waitcnt vmcnt(0)" ::: "memory");
  __syncthreads();

  #pragma unroll
  for (int kk = 0; kk < 8; ++kk) {
    bf16x8 bf[4], af[4];
    #pragma unroll
    for (int ni = 0; ni < 4; ++ni)
      bf[ni] = *(const bf16x8*)(WpB + ((kk * 4 + ni) * 64 + l) * 8);
    #pragma unroll
    for (int mi = 0; mi < 4; ++mi)
      af[mi] = *(const bf16x8*)(AlB + arow + mi * 8192 + ((((kk << 2) | g) ^ lmx) << 4));
    #pragma unroll
    for (int mi = 0; mi < 4; ++mi)
      #pragma unroll
      for (int ni = 0; ni < 4; ++ni)
        acc[mi][ni] = __builtin_amdgcn_mfma_f32_16x16x32_bf16(bf[ni], af[mi], acc[mi][ni], 0, 0, 0);
  }

  // pass 1: residual, store out, per-row partial stats
  int orow_[4];
  #pragma unroll
  for (int mi = 0; mi < 4; ++mi) {
    int grow = mt * 64 + mi * 16 + lm;
    int orow = win_row_to_token(grow);
    orow_[mi] = orow;
    const f32x4* xr = (const f32x4*)(xres + (size_t)orow * 256 + colb);
    f32x4* op = (f32x4*)(outf + (size_t)orow * 256 + colb);
    float s = 0.0f, sq = 0.0f;
    #pragma unroll
    for (int ni = 0; ni < 4; ++ni) {
      f32x4 r = xr[ni * 4] + acc[mi][ni];
      acc[mi][ni] = r;
      op[ni * 4] = r;
      #pragma unroll
      for (int j = 0; j < 4; ++j) { s += r[j]; sq += r[j] * r[j]; }
    }
    s  += __shfl_xor(s, 16);  sq += __shfl_xor(sq, 16);
    s  += __shfl_xor(s, 32);  sq += __shfl_xor(sq, 32);
    if (g == 0) Sst[mi][lm][w] = float2{s, sq};
  }
  __syncthreads();

  // pass 2: finalize LN2, write A_ln
  f32x4 g2v[4], b2v[4];
  #pragma unroll
  for (int ni = 0; ni < 4; ++ni) {
    g2v[ni] = *(const f32x4*)&g2[colb + ni * 16];
    b2v[ni] = *(const f32x4*)&b2[colb + ni * 16];
  }
  #pragma unroll
  for (int mi = 0; mi < 4; ++mi) {
    float s = 0.0f, sq = 0.0f;
    #pragma unroll
    for (int ww = 0; ww < 4; ++ww) { float2 t = Sst[mi][lm][ww]; s += t.x; sq += t.y; }
    float mu = s * (1.0f / 256.0f);
    float rs = rsqrtf(sq * (1.0f / 256.0f) - mu * mu + 1e-5f);
    __hip_bfloat16* ap = alnout + (size_t)orow_[mi] * 256 + colb;
    #pragma unroll
    for (int ni = 0; ni < 4; ++ni) {
      u16x4 st;
      #pragma unroll
      for (int j = 0; j < 4; ++j)
        st[j] = f2bf((acc[mi][ni][j] - mu) * rs * g2v[ni][j] + b2v[ni][j]);
      *(u16x4*)(ap + ni * 16) = st;
    }
  }
}

// ------------- MLP fused v5: 8 waves (R16-validated layout) + depth-1 pipeline
//               (R18-validated skeleton). 512 THREADS — launch must match!
// waves: wr = w>>2 (row half, rows wr*32..+31), wc = w&3 (col quarter).
// acc1+acc2 = 64 VGPR; pipeline regs ~80 more; cap 256 at launch_bounds(512,2).
// 2 waves/SIMD inside the block overlap whatever chain the pipeline leaves.
__global__ __launch_bounds__(512, 2) void mlp_fused(
    const __hip_bfloat16* __restrict__ A,     // A_ln (token order)
    const __hip_bfloat16* __restrict__ W1p,   // packed N=1024 K=256
    const __hip_bfloat16* __restrict__ W2p,   // packed N=256 K=1024
    const float* __restrict__ bm1, const float* __restrict__ bm2,
    float* __restrict__ outf)
{
  __shared__ __align__(16) __hip_bfloat16 Al[64 * 256];   // 32KB
  __shared__ __align__(16) __hip_bfloat16 Hl[64 * 256];   // 32KB

  const int tid = threadIdx.x;
  const int w = tid >> 6, l = tid & 63;
  const int g = l >> 4, lm = l & 15;
  const int wr = w >> 2, wc = w & 3;

  const int nwg = gridDim.x;
  int bswz = (blockIdx.x & 7) * (nwg >> 3) + (blockIdx.x >> 3);
  const int mt = bswz;

  const char* At = (const char*)A + (size_t)mt * 64 * 512;
  char* AlB = (char*)Al;
  char* HlB = (char*)Hl;
  const int usw = ((tid & 31) ^ ((tid >> 5) & 7)) << 4;
  const int lmx = lm & 7;
  const int arow = (wr * 32 + lm) * 512;     // + mi*8192
  const int colb = wc * 64 + g * 4;

  // stage A-tile once: 2048 units, 512 thr -> 4 units each (R16-validated)
  #pragma unroll
  for (int j = 0; j < 4; ++j)
    __builtin_amdgcn_global_load_lds(
        (const AS1 void*)(At + (long)(j * 16 + (tid >> 5)) * 512 + usw),
        (AS3 void*)(AlB + j * 8192 + w * 1024), 16, 0, 0);
  asm volatile("s_waitcnt vmcnt(0)" ::: "memory");
  __syncthreads();

  f32x4 acc2[2][4];
  {
    f32x4 b2v[4];
    #pragma unroll
    for (int ni = 0; ni < 4; ++ni) b2v[ni] = *(const f32x4*)&bm2[colb + ni * 16];
    #pragma unroll
    for (int mi = 0; mi < 2; ++mi)
      #pragma unroll
      for (int ni = 0; ni < 4; ++ni) acc2[mi][ni] = b2v[ni];
  }

  #pragma unroll
  for (int q = 0; q < 4; ++q) {
    const __hip_bfloat16* Wk1 = W1p + (size_t)(q * 4 + wc) * 16384;
    const __hip_bfloat16* Wk2 = W2p + (size_t)(wc * 4 + q) * 16384;

    // ---- GEMM1 quarter (software-pipelined kk) ----
    f32x4 acc1[2][4];
    {
      f32x4 b1v[4];
      #pragma unroll
      for (int ni = 0; ni < 4; ++ni) b1v[ni] = *(const f32x4*)&bm1[q * 256 + colb + ni * 16];
      #pragma unroll
      for (int mi = 0; mi < 2; ++mi)
        #pragma unroll
        for (int ni = 0; ni < 4; ++ni) acc1[mi][ni] = b1v[ni];
    }
    bf16x8 bfc[4], afc[2], bfn[4], afn[2];
    #pragma unroll
    for (int ni = 0; ni < 4; ++ni)
      bfc[ni] = *(const bf16x8*)(Wk1 + (ni * 64 + l) * 8);
    #pragma unroll
    for (int mi = 0; mi < 2; ++mi)
      afc[mi] = *(const bf16x8*)(AlB + arow + mi * 8192 + ((g ^ lmx) << 4));
    #pragma unroll
    for (int kk = 0; kk < 8; ++kk) {
      if (kk < 7) {
        #pragma unroll
        for (int ni = 0; ni < 4; ++ni)
          bfn[ni] = *(const bf16x8*)(Wk1 + (((kk + 1) * 4 + ni) * 64 + l) * 8);
        #pragma unroll
        for (int mi = 0; mi < 2; ++mi)
          afn[mi] = *(const bf16x8*)(AlB + arow + mi * 8192 +
                                     (((((kk + 1) << 2) | g) ^ lmx) << 4));
      }
      #pragma unroll
      for (int mi = 0; mi < 2; ++mi)
        #pragma unroll
        for (int ni = 0; ni < 4; ++ni)
          acc1[mi][ni] = __builtin_amdgcn_mfma_f32_16x16x32_bf16(bfc[ni], afc[mi], acc1[mi][ni], 0, 0, 0);
      #pragma unroll
      for (int ni = 0; ni < 4; ++ni) bfc[ni] = bfn[ni];
      #pragma unroll
      for (int mi = 0; mi < 2; ++mi) afc[mi] = afn[mi];
    }

    // prefetch GEMM2's kk=0 W-frags: independent of Hl, flies under GELU+barrier
    #pragma unroll
    for (int ni = 0; ni < 4; ++ni)
      bfc[ni] = *(const bf16x8*)(Wk2 + (ni * 64 + l) * 8);

    __syncthreads();   // prior quarter's GEMM2 reads of Hl are done
    // ---- GELU -> Hl (R16-validated swizzled layout; rows wr*32+mi*16+lm) ----
    #pragma unroll
    for (int mi = 0; mi < 2; ++mi) {
      int rowb = arow + mi * 8192;
      #pragma unroll
      for (int ni = 0; ni < 4; ++ni) {
        u16x4 hv = { f2bf(gelu_t(acc1[mi][ni][0])), f2bf(gelu_t(acc1[mi][ni][1])),
                     f2bf(gelu_t(acc1[mi][ni][2])), f2bf(gelu_t(acc1[mi][ni][3])) };
        int unit = (wc * 8 + ni * 2 + (g >> 1)) ^ lmx;
        *(u16x4*)(HlB + rowb + unit * 16 + (g & 1) * 8) = hv;
      }
    }
    __syncthreads();

    // ---- GEMM2 partial: kb = q (software-pipelined kk) ----
    #pragma unroll
    for (int mi = 0; mi < 2; ++mi)
      afc[mi] = *(const bf16x8*)(HlB + arow + mi * 8192 + ((g ^ lmx) << 4));
    #pragma unroll
    for (int kk = 0; kk < 8; ++kk) {
      if (kk < 7) {
        #pragma unroll
        for (int ni = 0; ni < 4; ++ni)
          bfn[ni] = *(const bf16x8*)(Wk2 + (((kk + 1) * 4 + ni) * 64 + l) * 8);
        #pragma unroll
        for (int mi = 0; mi < 2; ++mi)
          afn[mi] = *(const bf16x8*)(HlB + arow + mi * 8192 +
                                     (((((kk + 1) << 2) | g) ^ lmx) << 4));
      }
      #pragma unroll
      for (int mi = 0; mi < 2; ++mi)
        #pragma unroll
        for (int ni = 0; ni < 4; ++ni)
          acc2[mi][ni] = __builtin_amdgcn_mfma_f32_16x16x32_bf16(bfc[ni], afc[mi], acc2[mi][ni], 0, 0, 0);
      #pragma unroll
      for (int ni = 0; ni < 4; ++ni) bfc[ni] = bfn[ni];
      #pragma unroll
      for (int mi = 0; mi < 2; ++mi) afc[mi] = afn[mi];
    }
  }

  // ---- epilogue: out += acc2 (bias already in init) ----
  #pragma unroll
  for (int mi = 0; mi < 2; ++mi) {
    int grow = mt * 64 + wr * 32 + mi * 16 + lm;
    f32x4* op = (f32x4*)(outf + (size_t)grow * 256 + colb);
    #pragma unroll
    for (int ni = 0; ni < 4; ++ni)
      op[ni * 4] = op[ni * 4] + acc2[mi][ni];
  }
}

// ---------------- Sadd precompute: bias+mask in MFMA frag layout ----------------
__global__ __launch_bounds__(256) void bias_prep_kernel(
    const float* __restrict__ bt, float* __restrict__ Sadd)
{
  int blk = blockIdx.x;            // class*8 + h
  int cls = blk >> 3, h = blk & 7;
  int re = cls >> 1, ce = cls & 1;
  int lane = threadIdx.x & 63, fs = threadIdx.x >> 6;
  int g = lane >> 4, lm = lane & 15;
  #pragma unroll
  for (int i = 0; i < 4; ++i) {
    int f = fs * 4 + i;
    int mi = f >> 2, ni = f & 3;
    int key = ni * 16 + lm;
    f32x4 v;
    #pragma unroll
    for (int j = 0; j < 4; ++j) {
      int q = mi * 16 + g * 4 + j;
      float val;
      if (key >= 49) {
        val = -1e30f;
      } else {
        int qq = q > 48 ? 48 : q;
        int qh = qq / 7, qw = qq - qh * 7;
        int kh = key / 7, kw = key - kh * 7;
        int rpi = (qh - kh + 6) * 13 + (qw - kw + 6);
        val = bt[rpi * 8 + h];
        int rq = (re ? (qh < 4 ? 1 : 2) : 0) * 3 + (ce ? (qw < 4 ? 1 : 2) : 0);
        int rk = (re ? (kh < 4 ? 1 : 2) : 0) * 3 + (ce ? (kw < 4 ? 1 : 2) : 0);
        if (rq != rk) val -= 100.0f;
      }
      v[j] = val;
    }
    ((f32x4*)Sadd)[(blk * 16 + f) * 64 + lane] = v;
  }
}

// ---------------- MFMA attention: block = (window, 4 heads), wave = head ----------
__global__ __launch_bounds__(256) void attn_mfma_kernel(
    const __hip_bfloat16* __restrict__ qkv,
    const float* __restrict__ Sadd,
    __hip_bfloat16* __restrict__ attn_out)
{
  __shared__ __align__(16) __hip_bfloat16 Pl[4][64 * 72];
  int blk = blockIdx.x;
  int win = blk >> 1, half = blk & 1;
  int w = threadIdx.x >> 6, l = threadIdx.x & 63;
  int head = half * 4 + w;
  int g = l >> 4, lm = l & 15;
  int wi = win & 63;
  int cls = (((wi >> 3) == 7) ? 2 : 0) | (((wi & 7) == 7) ? 1 : 0);
  const __hip_bfloat16* base = qkv + (size_t)win * 49 * 768 + head * 32;

  bf16x8 aQ[4], bK[4];
  #pragma unroll
  for (int mi = 0; mi < 4; ++mi) {
    int q = mi * 16 + lm; if (q > 48) q = 48;
    aQ[mi] = *(const bf16x8*)(base + q * 768 + g * 8);
  }
  #pragma unroll
  for (int ni = 0; ni < 4; ++ni) {
    int k = ni * 16 + lm; if (k > 48) k = 48;
    bK[ni] = *(const bf16x8*)(base + 256 + k * 768 + g * 8);
  }
  f32x4 acc[4][4] = {};
  #pragma unroll
  for (int mi = 0; mi < 4; ++mi)
    #pragma unroll
    for (int ni = 0; ni < 4; ++ni)
      acc[mi][ni] = __builtin_amdgcn_mfma_f32_16x16x32_bf16(aQ[mi], bK[ni], acc[mi][ni], 0, 0, 0);

  const float scale = 0.17677669529663687f;
  const f32x4* Sb = (const f32x4*)Sadd + (size_t)(cls * 8 + head) * 16 * 64 + l;

  f32x4 rsum[4];
  __hip_bfloat16* P = Pl[w];
  #pragma unroll
  for (int mi = 0; mi < 4; ++mi) {
    #pragma unroll
    for (int ni = 0; ni < 4; ++ni) {
      f32x4 sv = Sb[(mi * 4 + ni) * 64];
      #pragma unroll
      for (int j = 0; j < 4; ++j) acc[mi][ni][j] = acc[mi][ni][j] * scale + sv[j];
    }
    f32x4 mx = acc[mi][0];
    #pragma unroll
    for (int ni = 1; ni < 4; ++ni)
      #pragma unroll
      for (int j = 0; j < 4; ++j) mx[j] = fmaxf(mx[j], acc[mi][ni][j]);
    #pragma unroll
    for (int msk = 1; msk < 16; msk <<= 1)
      #pragma unroll
      for (int j = 0; j < 4; ++j) mx[j] = fmaxf(mx[j], __shfl_xor(mx[j], msk));
    f32x4 sm = {};
    #pragma unroll
    for (int ni = 0; ni < 4; ++ni)
      #pragma unroll
      for (int j = 0; j < 4; ++j) {
        float e = __expf(acc[mi][ni][j] - mx[j]);
        acc[mi][ni][j] = e;
        sm[j] += e;
      }
    #pragma unroll
    for (int msk = 1; msk < 16; msk <<= 1)
      #pragma unroll
      for (int j = 0; j < 4; ++j) sm[j] += __shfl_xor(sm[j], msk);
    rsum[mi] = sm;
    #pragma unroll
    for (int ni = 0; ni < 4; ++ni)
      #pragma unroll
      for (int j = 0; j < 4; ++j) {
        int q = mi * 16 + g * 4 + j;
        int key = ni * 16 + lm;
        P[q * 72 + key] = __float2bfloat16(acc[mi][ni][j]);
      }
  }

  bf16x8 bV[2][2];
  #pragma unroll
  for (int s = 0; s < 2; ++s)
    #pragma unroll
    for (int n2 = 0; n2 < 2; ++n2) {
      bf16x8 vv;
      #pragma unroll
      for (int e = 0; e < 8; ++e) {
        int key = s * 32 + g * 8 + e; if (key > 48) key = 48;
        vv[e] = __builtin_bit_cast(short, base[512 + key * 768 + n2 * 16 + lm]);
      }
      bV[s][n2] = vv;
    }

  f32x4 o[4][2] = {};
  #pragma unroll
  for (int s = 0; s < 2; ++s)
    #pragma unroll
    for (int mi2 = 0; mi2 < 4; ++mi2) {
      bf16x8 aP = *(const bf16x8*)&P[(mi2 * 16 + lm) * 72 + s * 32 + g * 8];
      #pragma unroll
      for (int n2 = 0; n2 < 2; ++n2)
        o[mi2][n2] = __builtin_amdgcn_mfma_f32_16x16x32_bf16(aP, bV[s][n2], o[mi2][n2], 0, 0, 0);
    }

  #pragma unroll
  for (int mi2 = 0; mi2 < 4; ++mi2) {
    f32x4 li;
    #pragma unroll
    for (int j = 0; j < 4; ++j) li[j] = 1.0f / rsum[mi2][j];
    #pragma unroll
    for (int n2 = 0; n2 < 2; ++n2)
      #pragma unroll
      for (int j = 0; j < 4; ++j) {
        int q = mi2 * 16 + g * 4 + j;
        if (q < 49)
          attn_out[((size_t)win * 49 + q) * 256 + head * 32 + n2 * 16 + lm] =
              __float2bfloat16(o[mi2][n2][j] * li[j]);
      }
  }
}

// ---------------- host launch ----------------
extern "C" void kernel_launch(void* const* d_in, const int* in_sizes, int n_in,
                              void* d_out, int out_size, void* d_ws, size_t ws_size,
                              hipStream_t stream) {
  const float* x          = (const float*)d_in[0];
  const float* g1         = (const float*)d_in[1];
  const float* b1         = (const float*)d_in[2];
  const float* qkv_w      = (const float*)d_in[3];
  const float* qkv_b      = (const float*)d_in[4];
  const float* bias_table = (const float*)d_in[5];
  const float* proj_w     = (const float*)d_in[6];
  const float* proj_b     = (const float*)d_in[7];
  const float* g2         = (const float*)d_in[8];
  const float* b2         = (const float*)d_in[9];
  const float* w1         = (const float*)d_in[10];
  const float* bm1        = (const float*)d_in[11];
  const float* w2         = (const float*)d_in[12];
  const float* bm2        = (const float*)d_in[13];
  float* out = (float*)d_out;

  char* ws = (char*)d_ws;
  __hip_bfloat16* A_ln   = (__hip_bfloat16*)(ws);
  __hip_bfloat16* qkvb   = (__hip_bfloat16*)(ws + 51380224);
  __hip_bfloat16* attn_o = (__hip_bfloat16*)(ws + 205520896);
  __hip_bfloat16* qkv_wb  = (__hip_bfloat16*)(ws + 256901120);
  __hip_bfloat16* proj_wb = qkv_wb + 196608;
  __hip_bfloat16* w1b     = proj_wb + 65536;
  __hip_bfloat16* w2b     = w1b + 262144;
  float* Sadd = (float*)(ws + 258473984);

  pack_kernel<<<(196608 / 8 + 255) / 256, 256, 0, stream>>>(qkv_w, qkv_wb, 768, 256);
  pack_kernel<<<(65536  / 8 + 255) / 256, 256, 0, stream>>>(proj_w, proj_wb, 256, 256);
  pack_kernel<<<(262144 / 8 + 255) / 256, 256, 0, stream>>>(w1, w1b, 1024, 256);
  pack_kernel<<<(262144 / 8 + 255) / 256, 256, 0, stream>>>(w2, w2b, 256, 1024);
  bias_prep_kernel<<<32, 256, 0, stream>>>(bias_table, Sadd);

  ln_kernel<<<MROWS / 4, 256, 0, stream>>>(x, g1, b1, A_ln);

  gemm_qkv<<<1568 * 3, 256, 0, stream>>>(A_ln, qkv_wb, qkv_b, qkvb);

  attn_mfma_kernel<<<4096, 256, 0, stream>>>(qkvb, Sadd, attn_o);

  proj_ln2<<<1568, 256, 0, stream>>>(attn_o, proj_wb, proj_b, x, g2, b2, out, A_ln);

  // v5 is an 8-wave kernel: 512 THREADS (R15 lesson — launch must match).
  mlp_fused<<<1568, 512, 0, stream>>>(A_ln, w1b, w2b, bm1, bm2, out);
}

// Round 22
// 452.952 us; speedup vs baseline: 1.0553x; 1.0553x over previous
//
#include <hip/hip_runtime.h>
#include <hip/hip_bf16.h>

#define DEVI __device__ __forceinline__
#define AS1 __attribute__((address_space(1)))
#define AS3 __attribute__((address_space(3)))

typedef short bf16x8 __attribute__((ext_vector_type(8)));
typedef float f32x4  __attribute__((ext_vector_type(4)));
typedef unsigned short u16x4 __attribute__((ext_vector_type(4)));

// Problem constants (B=32, H=W=56, C=256, wh=ww=7, shift=3, heads=8, hd=32)
constexpr int MROWS = 100352;            // 32 * 64 * 49 window-order rows

// window-order row -> flat token index (b*3136 + h*56 + w).
DEVI int win_row_to_token(int r) {
  int b   = r / 3136;
  int rem = r - b * 3136;
  int wi  = rem / 49;
  int t   = rem - wi * 49;
  int nwh = wi >> 3, nww = wi & 7;
  int th = t / 7, tw = t - th * 7;
  int h = nwh * 7 + th + 3; if (h >= 56) h -= 56;
  int w = nww * 7 + tw + 3; if (w >= 56) w -= 56;
  return b * 3136 + h * 56 + w;
}

DEVI unsigned short f2bf(float f) {
  __hip_bfloat16 h = __float2bfloat16(f);
  return __builtin_bit_cast(unsigned short, h);
}

DEVI float gelu_t(float v) {
  // tanh-form GELU: v * sigmoid(2*0.7978845608*(v + 0.044715 v^3))
  float u2 = v * (1.5957691216f + 0.1426930877f * v * v);
  float e  = __expf(u2);
  return v * e / (e + 1.0f);
}

// -------- pack W (fp32 [N][K]) -> MFMA-frag-ordered bf16 --------
__global__ void pack_kernel(const float* __restrict__ W, __hip_bfloat16* __restrict__ Wp,
                            int N, int K) {
  long t = (long)blockIdx.x * 256 + threadIdx.x;   // one bf16x8 per thread
  long total = (long)N * K / 8;
  if (t >= total) return;
  int l  = (int)(t & 63);
  long f = t >> 6;
  int ni = (int)(f & 3);
  int kk = (int)((f >> 2) & 7);
  long r = f >> 5;                 // nb*KB + kb
  int KB = K / 256;
  int kb = (int)(r % KB);
  int nb = (int)(r / KB);
  int row  = nb * 64 + (l & 15) + ni * 16;
  int col0 = kb * 256 + kk * 32 + (l >> 4) * 8;
  const float* src = W + (size_t)row * K + col0;
  u16x4 lo, hi;
  #pragma unroll
  for (int e = 0; e < 4; ++e) { lo[e] = f2bf(src[e]); hi[e] = f2bf(src[4 + e]); }
  *(u16x4*)(Wp + t * 8)     = lo;
  *(u16x4*)(Wp + t * 8 + 4) = hi;
}

// ---------------- LayerNorm 1 (one wave per token row, windowed gather) ----------------
__global__ __launch_bounds__(256) void ln_kernel(
    const float* __restrict__ xin, const float* __restrict__ g,
    const float* __restrict__ b, __hip_bfloat16* __restrict__ outb)
{
  int r = blockIdx.x * 4 + (threadIdx.x >> 6);
  int l = threadIdx.x & 63;
  int tok = win_row_to_token(r);
  float4 xv = *(const float4*)&xin[(size_t)tok * 256 + l * 4];
  float s = xv.x + xv.y + xv.z + xv.w;
  float q = xv.x * xv.x + xv.y * xv.y + xv.z * xv.z + xv.w * xv.w;
  #pragma unroll
  for (int off = 32; off; off >>= 1) { s += __shfl_xor(s, off); q += __shfl_xor(q, off); }
  float mu = s * (1.0f / 256.0f);
  float var = q * (1.0f / 256.0f) - mu * mu;
  float rs = rsqrtf(var + 1e-5f);
  float4 gv = *(const float4*)&g[l * 4];
  float4 bv = *(const float4*)&b[l * 4];
  ushort4 st;
  st.x = f2bf((xv.x - mu) * rs * gv.x + bv.x);
  st.y = f2bf((xv.y - mu) * rs * gv.y + bv.y);
  st.z = f2bf((xv.z - mu) * rs * gv.z + bv.z);
  st.w = f2bf((xv.w - mu) * rs * gv.w + bv.w);
  *(ushort4*)&outb[(size_t)r * 256 + l * 4] = st;
}

// ------------- A-resident GEMM for QKV (R13-validated) -------------
__global__ __launch_bounds__(256, 3) void gemm_qkv(
    const __hip_bfloat16* __restrict__ A,
    const __hip_bfloat16* __restrict__ Wp,   // frag-packed, N=768 K=256
    const float* __restrict__ bias,
    __hip_bfloat16* __restrict__ outb)
{
  constexpr int CB = 3;
  __shared__ __align__(16) __hip_bfloat16 Al[64 * 256];   // 32KB

  const int tid = threadIdx.x;
  const int w = tid >> 6, l = tid & 63;
  const int g = l >> 4, lm = l & 15;

  const int nwg = gridDim.x;
  int bswz = (blockIdx.x & 7) * (nwg >> 3) + (blockIdx.x >> 3);
  const int mt = bswz / CB;
  const int cb = bswz - mt * CB;

  const char* At = (const char*)A + (size_t)mt * 64 * 512;
  char* AlB = (char*)Al;
  const int r0  = tid >> 5;
  const int usw = ((tid & 31) ^ r0) << 4;
  const int lmx = lm & 7;
  const int arow = lm * 512;

  const __hip_bfloat16* WpB = Wp + (size_t)(cb * 4 + w) * 16384;
  const int colb = cb * 256 + w * 64 + g * 4;

  f32x4 acc[4][4];
  {
    f32x4 bias_v[4];
    #pragma unroll
    for (int ni = 0; ni < 4; ++ni) bias_v[ni] = *(const f32x4*)&bias[colb + ni * 16];
    #pragma unroll
    for (int mi = 0; mi < 4; ++mi)
      #pragma unroll
      for (int ni = 0; ni < 4; ++ni) acc[mi][ni] = bias_v[ni];
  }

  #pragma unroll
  for (int j = 0; j < 8; ++j)
    __builtin_amdgcn_global_load_lds(
        (const AS1 void*)(At + (long)(j * 8 + r0) * 512 + usw),
        (AS3 void*)(AlB + j * 4096 + w * 1024), 16, 0, 0);
  asm volatile("s_waitcnt vmcnt(0)" ::: "memory");
  __syncthreads();

  #pragma unroll
  for (int kk = 0; kk < 8; ++kk) {
    bf16x8 bf[4], af[4];
    #pragma unroll
    for (int ni = 0; ni < 4; ++ni)
      bf[ni] = *(const bf16x8*)(WpB + ((kk * 4 + ni) * 64 + l) * 8);
    #pragma unroll
    for (int mi = 0; mi < 4; ++mi)
      af[mi] = *(const bf16x8*)(AlB + arow + mi * 8192 + ((((kk << 2) | g) ^ lmx) << 4));
    #pragma unroll
    for (int mi = 0; mi < 4; ++mi)
      #pragma unroll
      for (int ni = 0; ni < 4; ++ni)
        acc[mi][ni] = __builtin_amdgcn_mfma_f32_16x16x32_bf16(bf[ni], af[mi], acc[mi][ni], 0, 0, 0);
  }

  #pragma unroll
  for (int mi = 0; mi < 4; ++mi) {
    int grow = mt * 64 + mi * 16 + lm;
    __hip_bfloat16* rp = outb + (size_t)grow * 768 + colb;
    #pragma unroll
    for (int ni = 0; ni < 4; ++ni) {
      u16x4 st = { f2bf(acc[mi][ni][0]), f2bf(acc[mi][ni][1]),
                   f2bf(acc[mi][ni][2]), f2bf(acc[mi][ni][3]) };
      *(u16x4*)(rp + ni * 16) = st;
    }
  }
}

// ------------- PROJ + residual + LN2 fused (R14-validated) -------------
__global__ __launch_bounds__(256, 3) void proj_ln2(
    const __hip_bfloat16* __restrict__ A,    // attn_o (window order)
    const __hip_bfloat16* __restrict__ Wp,   // frag-packed proj, N=256 K=256
    const float* __restrict__ bias,
    const float* __restrict__ xres,          // x (token order)
    const float* __restrict__ g2, const float* __restrict__ b2,
    float* __restrict__ outf,
    __hip_bfloat16* __restrict__ alnout)
{
  __shared__ __align__(16) __hip_bfloat16 Al[64 * 256];   // 32KB
  __shared__ float2 Sst[4][16][4];                        // 2KB (mi, lm, w)

  const int tid = threadIdx.x;
  const int w = tid >> 6, l = tid & 63;
  const int g = l >> 4, lm = l & 15;

  const int nwg = gridDim.x;
  int bswz = (blockIdx.x & 7) * (nwg >> 3) + (blockIdx.x >> 3);
  const int mt = bswz;

  const char* At = (const char*)A + (size_t)mt * 64 * 512;
  char* AlB = (char*)Al;
  const int r0  = tid >> 5;
  const int usw = ((tid & 31) ^ r0) << 4;
  const int lmx = lm & 7;
  const int arow = lm * 512;

  const __hip_bfloat16* WpB = Wp + (size_t)w * 16384;
  const int colb = w * 64 + g * 4;

  f32x4 acc[4][4];
  {
    f32x4 bias_v[4];
    #pragma unroll
    for (int ni = 0; ni < 4; ++ni) bias_v[ni] = *(const f32x4*)&bias[colb + ni * 16];
    #pragma unroll
    for (int mi = 0; mi < 4; ++mi)
      #pragma unroll
      for (int ni = 0; ni < 4; ++ni) acc[mi][ni] = bias_v[ni];
  }

  #pragma unroll
  for (int j = 0; j < 8; ++j)
    __builtin_amdgcn_global_load_lds(
        (const AS1 void*)(At + (long)(j * 8 + r0) * 512 + usw),
        (AS3 void*)(AlB + j * 4096 + w * 1024), 16, 0, 0);
  asm volatile("s_waitcnt vmcnt(0)" ::: "memory");
  __syncthreads();

  #pragma unroll
  for (int kk = 0; kk < 8; ++kk) {
    bf16x8 bf[4], af[4];
    #pragma unroll
    for (int ni = 0; ni < 4; ++ni)
      bf[ni] = *(const bf16x8*)(WpB + ((kk * 4 + ni) * 64 + l) * 8);
    #pragma unroll
    for (int mi = 0; mi < 4; ++mi)
      af[mi] = *(const bf16x8*)(AlB + arow + mi * 8192 + ((((kk << 2) | g) ^ lmx) << 4));
    #pragma unroll
    for (int mi = 0; mi < 4; ++mi)
      #pragma unroll
      for (int ni = 0; ni < 4; ++ni)
        acc[mi][ni] = __builtin_amdgcn_mfma_f32_16x16x32_bf16(bf[ni], af[mi], acc[mi][ni], 0, 0, 0);
  }

  // pass 1: residual, store out, per-row partial stats
  int orow_[4];
  #pragma unroll
  for (int mi = 0; mi < 4; ++mi) {
    int grow = mt * 64 + mi * 16 + lm;
    int orow = win_row_to_token(grow);
    orow_[mi] = orow;
    const f32x4* xr = (const f32x4*)(xres + (size_t)orow * 256 + colb);
    f32x4* op = (f32x4*)(outf + (size_t)orow * 256 + colb);
    float s = 0.0f, sq = 0.0f;
    #pragma unroll
    for (int ni = 0; ni < 4; ++ni) {
      f32x4 r = xr[ni * 4] + acc[mi][ni];
      acc[mi][ni] = r;
      op[ni * 4] = r;
      #pragma unroll
      for (int j = 0; j < 4; ++j) { s += r[j]; sq += r[j] * r[j]; }
    }
    s  += __shfl_xor(s, 16);  sq += __shfl_xor(sq, 16);
    s  += __shfl_xor(s, 32);  sq += __shfl_xor(sq, 32);
    if (g == 0) Sst[mi][lm][w] = float2{s, sq};
  }
  __syncthreads();

  // pass 2: finalize LN2, write A_ln
  f32x4 g2v[4], b2v[4];
  #pragma unroll
  for (int ni = 0; ni < 4; ++ni) {
    g2v[ni] = *(const f32x4*)&g2[colb + ni * 16];
    b2v[ni] = *(const f32x4*)&b2[colb + ni * 16];
  }
  #pragma unroll
  for (int mi = 0; mi < 4; ++mi) {
    float s = 0.0f, sq = 0.0f;
    #pragma unroll
    for (int ww = 0; ww < 4; ++ww) { float2 t = Sst[mi][lm][ww]; s += t.x; sq += t.y; }
    float mu = s * (1.0f / 256.0f);
    float rs = rsqrtf(sq * (1.0f / 256.0f) - mu * mu + 1e-5f);
    __hip_bfloat16* ap = alnout + (size_t)orow_[mi] * 256 + colb;
    #pragma unroll
    for (int ni = 0; ni < 4; ++ni) {
      u16x4 st;
      #pragma unroll
      for (int j = 0; j < 4; ++j)
        st[j] = f2bf((acc[mi][ni][j] - mu) * rs * g2v[ni][j] + b2v[ni][j]);
      *(u16x4*)(ap + ni * 16) = st;
    }
  }
}

// ------------- MLP fused v4 (R18): depth-1 software pipeline -------------
__global__ __launch_bounds__(256, 1) void mlp_fused(
    const __hip_bfloat16* __restrict__ A,     // A_ln (token order)
    const __hip_bfloat16* __restrict__ W1p,   // packed N=1024 K=256
    const __hip_bfloat16* __restrict__ W2p,   // packed N=256 K=1024
    const float* __restrict__ bm1, const float* __restrict__ bm2,
    float* __restrict__ outf)
{
  __shared__ __align__(16) __hip_bfloat16 Al[64 * 256];   // 32KB
  __shared__ __align__(16) __hip_bfloat16 Hl[64 * 256];   // 32KB

  const int tid = threadIdx.x;
  const int w = tid >> 6, l = tid & 63;
  const int g = l >> 4, lm = l & 15;

  const int nwg = gridDim.x;
  int bswz = (blockIdx.x & 7) * (nwg >> 3) + (blockIdx.x >> 3);
  const int mt = bswz;

  const char* At = (const char*)A + (size_t)mt * 64 * 512;
  char* AlB = (char*)Al;
  char* HlB = (char*)Hl;
  const int usw = ((tid & 31) ^ ((tid >> 5) & 7)) << 4;
  const int lmx = lm & 7;
  const int arow = lm * 512;                 // + mi*8192
  const int colb = w * 64 + g * 4;

  // stage A-tile once
  #pragma unroll
  for (int j = 0; j < 8; ++j)
    __builtin_amdgcn_global_load_lds(
        (const AS1 void*)(At + (long)(j * 8 + (tid >> 5)) * 512 + usw),
        (AS3 void*)(AlB + j * 4096 + w * 1024), 16, 0, 0);
  asm volatile("s_waitcnt vmcnt(0)" ::: "memory");
  __syncthreads();

  f32x4 acc2[4][4];
  {
    f32x4 b2v[4];
    #pragma unroll
    for (int ni = 0; ni < 4; ++ni) b2v[ni] = *(const f32x4*)&bm2[colb + ni * 16];
    #pragma unroll
    for (int mi = 0; mi < 4; ++mi)
      #pragma unroll
      for (int ni = 0; ni < 4; ++ni) acc2[mi][ni] = b2v[ni];
  }

  #pragma unroll
  for (int q = 0; q < 4; ++q) {
    const __hip_bfloat16* Wk1 = W1p + (size_t)(q * 4 + w) * 16384;
    const __hip_bfloat16* Wk2 = W2p + (size_t)(w * 4 + q) * 16384;

    // ---- GEMM1 quarter (software-pipelined kk) ----
    f32x4 acc1[4][4];
    {
      f32x4 b1v[4];
      #pragma unroll
      for (int ni = 0; ni < 4; ++ni) b1v[ni] = *(const f32x4*)&bm1[q * 256 + colb + ni * 16];
      #pragma unroll
      for (int mi = 0; mi < 4; ++mi)
        #pragma unroll
        for (int ni = 0; ni < 4; ++ni) acc1[mi][ni] = b1v[ni];
    }
    bf16x8 bfc[4], afc[4], bfn[4], afn[4];
    #pragma unroll
    for (int ni = 0; ni < 4; ++ni)
      bfc[ni] = *(const bf16x8*)(Wk1 + (ni * 64 + l) * 8);
    #pragma unroll
    for (int mi = 0; mi < 4; ++mi)
      afc[mi] = *(const bf16x8*)(AlB + arow + mi * 8192 + ((g ^ lmx) << 4));
    #pragma unroll
    for (int kk = 0; kk < 8; ++kk) {
      if (kk < 7) {
        #pragma unroll
        for (int ni = 0; ni < 4; ++ni)
          bfn[ni] = *(const bf16x8*)(Wk1 + (((kk + 1) * 4 + ni) * 64 + l) * 8);
        #pragma unroll
        for (int mi = 0; mi < 4; ++mi)
          afn[mi] = *(const bf16x8*)(AlB + arow + mi * 8192 +
                                     (((((kk + 1) << 2) | g) ^ lmx) << 4));
      }
      #pragma unroll
      for (int mi = 0; mi < 4; ++mi)
        #pragma unroll
        for (int ni = 0; ni < 4; ++ni)
          acc1[mi][ni] = __builtin_amdgcn_mfma_f32_16x16x32_bf16(bfc[ni], afc[mi], acc1[mi][ni], 0, 0, 0);
      #pragma unroll
      for (int ni = 0; ni < 4; ++ni) bfc[ni] = bfn[ni];
      #pragma unroll
      for (int mi = 0; mi < 4; ++mi) afc[mi] = afn[mi];
    }

    // prefetch GEMM2's kk=0 W-frags: independent of Hl, flies under GELU+barrier
    #pragma unroll
    for (int ni = 0; ni < 4; ++ni)
      bfc[ni] = *(const bf16x8*)(Wk2 + (ni * 64 + l) * 8);

    __syncthreads();   // prior quarter's GEMM2 reads of Hl are done
    // ---- GELU -> Hl (swizzled unit layout, R14-validated) ----
    #pragma unroll
    for (int mi = 0; mi < 4; ++mi) {
      int rowb = (mi * 16 + lm) * 512;
      #pragma unroll
      for (int ni = 0; ni < 4; ++ni) {
        u16x4 hv = { f2bf(gelu_t(acc1[mi][ni][0])), f2bf(gelu_t(acc1[mi][ni][1])),
                     f2bf(gelu_t(acc1[mi][ni][2])), f2bf(gelu_t(acc1[mi][ni][3])) };
        int unit = (w * 8 + ni * 2 + (g >> 1)) ^ lmx;
        *(u16x4*)(HlB + rowb + unit * 16 + (g & 1) * 8) = hv;
      }
    }
    __syncthreads();

    // ---- GEMM2 partial: kb = q (software-pipelined kk) ----
    #pragma unroll
    for (int mi = 0; mi < 4; ++mi)
      afc[mi] = *(const bf16x8*)(HlB + arow + mi * 8192 + ((g ^ lmx) << 4));
    #pragma unroll
    for (int kk = 0; kk < 8; ++kk) {
      if (kk < 7) {
        #pragma unroll
        for (int ni = 0; ni < 4; ++ni)
          bfn[ni] = *(const bf16x8*)(Wk2 + (((kk + 1) * 4 + ni) * 64 + l) * 8);
        #pragma unroll
        for (int mi = 0; mi < 4; ++mi)
          afn[mi] = *(const bf16x8*)(HlB + arow + mi * 8192 +
                                     (((((kk + 1) << 2) | g) ^ lmx) << 4));
      }
      #pragma unroll
      for (int mi = 0; mi < 4; ++mi)
        #pragma unroll
        for (int ni = 0; ni < 4; ++ni)
          acc2[mi][ni] = __builtin_amdgcn_mfma_f32_16x16x32_bf16(bfc[ni], afc[mi], acc2[mi][ni], 0, 0, 0);
      #pragma unroll
      for (int ni = 0; ni < 4; ++ni) bfc[ni] = bfn[ni];
      #pragma unroll
      for (int mi = 0; mi < 4; ++mi) afc[mi] = afn[mi];
    }
  }

  // ---- epilogue: out += acc2 (bias already in init) ----
  #pragma unroll
  for (int mi = 0; mi < 4; ++mi) {
    int grow = mt * 64 + mi * 16 + lm;
    f32x4* op = (f32x4*)(outf + (size_t)grow * 256 + colb);
    #pragma unroll
    for (int ni = 0; ni < 4; ++ni)
      op[ni * 4] = op[ni * 4] + acc2[mi][ni];
  }
}

// ---------------- Sadd precompute: bias+mask in MFMA frag layout ----------------
__global__ __launch_bounds__(256) void bias_prep_kernel(
    const float* __restrict__ bt, float* __restrict__ Sadd)
{
  int blk = blockIdx.x;            // class*8 + h
  int cls = blk >> 3, h = blk & 7;
  int re = cls >> 1, ce = cls & 1;
  int lane = threadIdx.x & 63, fs = threadIdx.x >> 6;
  int g = lane >> 4, lm = lane & 15;
  #pragma unroll
  for (int i = 0; i < 4; ++i) {
    int f = fs * 4 + i;
    int mi = f >> 2, ni = f & 3;
    int key = ni * 16 + lm;
    f32x4 v;
    #pragma unroll
    for (int j = 0; j < 4; ++j) {
      int q = mi * 16 + g * 4 + j;
      float val;
      if (key >= 49) {
        val = -1e30f;
      } else {
        int qq = q > 48 ? 48 : q;
        int qh = qq / 7, qw = qq - qh * 7;
        int kh = key / 7, kw = key - kh * 7;
        int rpi = (qh - kh + 6) * 13 + (qw - kw + 6);
        val = bt[rpi * 8 + h];
        int rq = (re ? (qh < 4 ? 1 : 2) : 0) * 3 + (ce ? (qw < 4 ? 1 : 2) : 0);
        int rk = (re ? (kh < 4 ? 1 : 2) : 0) * 3 + (ce ? (kw < 4 ? 1 : 2) : 0);
        if (rq != rk) val -= 100.0f;
      }
      v[j] = val;
    }
    ((f32x4*)Sadd)[(blk * 16 + f) * 64 + lane] = v;
  }
}

// ---------------- MFMA attention: block = (window, 4 heads), wave = head ----------
__global__ __launch_bounds__(256) void attn_mfma_kernel(
    const __hip_bfloat16* __restrict__ qkv,
    const float* __restrict__ Sadd,
    __hip_bfloat16* __restrict__ attn_out)
{
  __shared__ __align__(16) __hip_bfloat16 Pl[4][64 * 72];
  int blk = blockIdx.x;
  int win = blk >> 1, half = blk & 1;
  int w = threadIdx.x >> 6, l = threadIdx.x & 63;
  int head = half * 4 + w;
  int g = l >> 4, lm = l & 15;
  int wi = win & 63;
  int cls = (((wi >> 3) == 7) ? 2 : 0) | (((wi & 7) == 7) ? 1 : 0);
  const __hip_bfloat16* base = qkv + (size_t)win * 49 * 768 + head * 32;

  bf16x8 aQ[4], bK[4];
  #pragma unroll
  for (int mi = 0; mi < 4; ++mi) {
    int q = mi * 16 + lm; if (q > 48) q = 48;
    aQ[mi] = *(const bf16x8*)(base + q * 768 + g * 8);
  }
  #pragma unroll
  for (int ni = 0; ni < 4; ++ni) {
    int k = ni * 16 + lm; if (k > 48) k = 48;
    bK[ni] = *(const bf16x8*)(base + 256 + k * 768 + g * 8);
  }
  f32x4 acc[4][4] = {};
  #pragma unroll
  for (int mi = 0; mi < 4; ++mi)
    #pragma unroll
    for (int ni = 0; ni < 4; ++ni)
      acc[mi][ni] = __builtin_amdgcn_mfma_f32_16x16x32_bf16(aQ[mi], bK[ni], acc[mi][ni], 0, 0, 0);

  const float scale = 0.17677669529663687f;
  const f32x4* Sb = (const f32x4*)Sadd + (size_t)(cls * 8 + head) * 16 * 64 + l;

  f32x4 rsum[4];
  __hip_bfloat16* P = Pl[w];
  #pragma unroll
  for (int mi = 0; mi < 4; ++mi) {
    #pragma unroll
    for (int ni = 0; ni < 4; ++ni) {
      f32x4 sv = Sb[(mi * 4 + ni) * 64];
      #pragma unroll
      for (int j = 0; j < 4; ++j) acc[mi][ni][j] = acc[mi][ni][j] * scale + sv[j];
    }
    f32x4 mx = acc[mi][0];
    #pragma unroll
    for (int ni = 1; ni < 4; ++ni)
      #pragma unroll
      for (int j = 0; j < 4; ++j) mx[j] = fmaxf(mx[j], acc[mi][ni][j]);
    #pragma unroll
    for (int msk = 1; msk < 16; msk <<= 1)
      #pragma unroll
      for (int j = 0; j < 4; ++j) mx[j] = fmaxf(mx[j], __shfl_xor(mx[j], msk));
    f32x4 sm = {};
    #pragma unroll
    for (int ni = 0; ni < 4; ++ni)
      #pragma unroll
      for (int j = 0; j < 4; ++j) {
        float e = __expf(acc[mi][ni][j] - mx[j]);
        acc[mi][ni][j] = e;
        sm[j] += e;
      }
    #pragma unroll
    for (int msk = 1; msk < 16; msk <<= 1)
      #pragma unroll
      for (int j = 0; j < 4; ++j) sm[j] += __shfl_xor(sm[j], msk);
    rsum[mi] = sm;
    #pragma unroll
    for (int ni = 0; ni < 4; ++ni)
      #pragma unroll
      for (int j = 0; j < 4; ++j) {
        int q = mi * 16 + g * 4 + j;
        int key = ni * 16 + lm;
        P[q * 72 + key] = __float2bfloat16(acc[mi][ni][j]);
      }
  }

  bf16x8 bV[2][2];
  #pragma unroll
  for (int s = 0; s < 2; ++s)
    #pragma unroll
    for (int n2 = 0; n2 < 2; ++n2) {
      bf16x8 vv;
      #pragma unroll
      for (int e = 0; e < 8; ++e) {
        int key = s * 32 + g * 8 + e; if (key > 48) key = 48;
        vv[e] = __builtin_bit_cast(short, base[512 + key * 768 + n2 * 16 + lm]);
      }
      bV[s][n2] = vv;
    }

  f32x4 o[4][2] = {};
  #pragma unroll
  for (int s = 0; s < 2; ++s)
    #pragma unroll
    for (int mi2 = 0; mi2 < 4; ++mi2) {
      bf16x8 aP = *(const bf16x8*)&P[(mi2 * 16 + lm) * 72 + s * 32 + g * 8];
      #pragma unroll
      for (int n2 = 0; n2 < 2; ++n2)
        o[mi2][n2] = __builtin_amdgcn_mfma_f32_16x16x32_bf16(aP, bV[s][n2], o[mi2][n2], 0, 0, 0);
    }

  #pragma unroll
  for (int mi2 = 0; mi2 < 4; ++mi2) {
    f32x4 li;
    #pragma unroll
    for (int j = 0; j < 4; ++j) li[j] = 1.0f / rsum[mi2][j];
    #pragma unroll
    for (int n2 = 0; n2 < 2; ++n2)
      #pragma unroll
      for (int j = 0; j < 4; ++j) {
        int q = mi2 * 16 + g * 4 + j;
        if (q < 49)
          attn_out[((size_t)win * 49 + q) * 256 + head * 32 + n2 * 16 + lm] =
              __float2bfloat16(o[mi2][n2][j] * li[j]);
      }
  }
}

// ---------------- host launch ----------------
extern "C" void kernel_launch(void* const* d_in, const int* in_sizes, int n_in,
                              void* d_out, int out_size, void* d_ws, size_t ws_size,
                              hipStream_t stream) {
  const float* x          = (const float*)d_in[0];
  const float* g1         = (const float*)d_in[1];
  const float* b1         = (const float*)d_in[2];
  const float* qkv_w      = (const float*)d_in[3];
  const float* qkv_b      = (const float*)d_in[4];
  const float* bias_table = (const float*)d_in[5];
  const float* proj_w     = (const float*)d_in[6];
  const float* proj_b     = (const float*)d_in[7];
  const float* g2         = (const float*)d_in[8];
  const float* b2         = (const float*)d_in[9];
  const float* w1         = (const float*)d_in[10];
  const float* bm1        = (const float*)d_in[11];
  const float* w2         = (const float*)d_in[12];
  const float* bm2        = (const float*)d_in[13];
  float* out = (float*)d_out;

  char* ws = (char*)d_ws;
  __hip_bfloat16* A_ln   = (__hip_bfloat16*)(ws);
  __hip_bfloat16* qkvb   = (__hip_bfloat16*)(ws + 51380224);
  __hip_bfloat16* attn_o = (__hip_bfloat16*)(ws + 205520896);
  __hip_bfloat16* qkv_wb  = (__hip_bfloat16*)(ws + 256901120);
  __hip_bfloat16* proj_wb = qkv_wb + 196608;
  __hip_bfloat16* w1b     = proj_wb + 65536;
  __hip_bfloat16* w2b     = w1b + 262144;
  float* Sadd = (float*)(ws + 258473984);

  pack_kernel<<<(196608 / 8 + 255) / 256, 256, 0, stream>>>(qkv_w, qkv_wb, 768, 256);
  pack_kernel<<<(65536  / 8 + 255) / 256, 256, 0, stream>>>(proj_w, proj_wb, 256, 256);
  pack_kernel<<<(262144 / 8 + 255) / 256, 256, 0, stream>>>(w1, w1b, 1024, 256);
  pack_kernel<<<(262144 / 8 + 255) / 256, 256, 0, stream>>>(w2, w2b, 256, 1024);
  bias_prep_kernel<<<32, 256, 0, stream>>>(bias_table, Sadd);

  ln_kernel<<<MROWS / 4, 256, 0, stream>>>(x, g1, b1, A_ln);

  gemm_qkv<<<1568 * 3, 256, 0, stream>>>(A_ln, qkv_wb, qkv_b, qkvb);

  attn_mfma_kernel<<<4096, 256, 0, stream>>>(qkvb, Sadd, attn_o);

  proj_ln2<<<1568, 256, 0, stream>>>(attn_o, proj_wb, proj_b, x, g2, b2, out, A_ln);

  mlp_fused<<<1568, 256, 0, stream>>>(A_ln, w1b, w2b, bm1, bm2, out);
}